// Round 10
// baseline (3530.467 us; speedup 1.0000x reference)
//
#include <hip/hip_runtime.h>
#include <hip/hip_bf16.h>

typedef __attribute__((ext_vector_type(4))) float f32x4;
typedef __attribute__((ext_vector_type(4))) int   i32x4;
typedef __attribute__((ext_vector_type(8))) short s16x8;
typedef __attribute__((ext_vector_type(4))) unsigned short u16x4;
typedef __attribute__((ext_vector_type(2))) unsigned int  u32x2;

#define T_ 512
#define B_ 8
#define H_ 128
#define V_ 32000

// ws layout (bytes)
#define WS_PRE0   0u          // [512][8][128] f32   2MB
#define WS_H1B    (2u<<20)    // [512][8][128] bf16  1MB
#define WS_H0G    (3u<<20)    // [512][8][128] bf16  1MB
#define WS_PIH    (4u<<20)    // [512][8 mt][64 lane] f32x4  4MB
#define WS_FCWB   (8u<<20)    // [32000][128] bf16   8MB
#define WS_FLAGS  (16u<<20)   // prog0 @+0, prog1[4] @+256, prog2 @+512, ctr @+768

#define NTILES 8000           // 4 tb x 250 nt x 8 bb
#define GRID_ALL 768          // 3 scan + 765 workers

// round-to-nearest-even f32 -> bf16
__device__ __forceinline__ unsigned short f2b(float f) {
  unsigned int u = __float_as_uint(f);
  u = (u + 0x7FFFu + ((u >> 16) & 1u)) >> 16;
  return (unsigned short)u;
}

__device__ __forceinline__ float hsum4(f32x4 v) { return (v.x + v.y) + (v.z + v.w); }

__device__ __forceinline__ float tanh_fast(float x) {
  float e = __expf(2.f * x);
  return 1.f - 2.f * __builtin_amdgcn_rcpf(e + 1.f);
}

__device__ __forceinline__ f32x4 tanh4(f32x4 v) {
  f32x4 r;
  r.x = tanh_fast(v.x); r.y = tanh_fast(v.y);
  r.z = tanh_fast(v.z); r.w = tanh_fast(v.w);
  return r;
}

// pack 4 f32 -> 4 bf16 (2 dwords), RNE
__device__ __forceinline__ u32x2 pk4(f32x4 v) {
  unsigned int a, b;
  asm("v_cvt_pk_bf16_f32 %0, %1, %2" : "=v"(a) : "v"(v.x), "v"(v.y));
  asm("v_cvt_pk_bf16_f32 %0, %1, %2" : "=v"(b) : "v"(v.z), "v"(v.w));
  u32x2 r; r.x = a; r.y = b; return r;
}

// barrier that does NOT drain vmcnt: LDS-only visibility + s_barrier.
__device__ __forceinline__ void lds_barrier() {
  asm volatile("s_waitcnt lgkmcnt(0)\n\ts_barrier" ::: "memory");
}

__device__ __forceinline__ unsigned int ld_flag_acq(const unsigned int* p) {
  return __hip_atomic_load(p, __ATOMIC_ACQUIRE, __HIP_MEMORY_SCOPE_AGENT);
}
__device__ __forceinline__ void flag_add_rel(unsigned int* p, unsigned int v) {
  __hip_atomic_fetch_add(p, v, __ATOMIC_RELEASE, __HIP_MEMORY_SCOPE_AGENT);
}

#define MFMA16(A, B, C) __builtin_amdgcn_mfma_f32_16x16x32_bf16((A), (B), (C), 0, 0, 0)

__device__ __forceinline__ int swz(int row, int cc) {
  return row * 256 + ((cc ^ (row & 7)) << 4);
}

// ---------------- fc_W f32 -> bf16 ----------------
__global__ __launch_bounds__(256) void convert_w_kernel(const float* __restrict__ src,
                                                        unsigned short* __restrict__ dst, int n4) {
  int idx = blockIdx.x * 256 + threadIdx.x;
  int stride = gridDim.x * 256;
  for (int c = idx; c < n4; c += stride) {
    f32x4 v = ((const f32x4*)src)[c];
    u16x4 o;
    o.x = f2b(v.x); o.y = f2b(v.y); o.z = f2b(v.z); o.w = f2b(v.w);
    ((u16x4*)dst)[c] = o;
  }
}

// ---------------- pre0 = emb[x] @ W_ih0^T + b_ih0 + b_hh0 ----------------
__global__ __launch_bounds__(128) void pre_kernel(const float* __restrict__ emb,
                                                  const int* __restrict__ x,
                                                  const float* __restrict__ W,
                                                  const float* __restrict__ b1,
                                                  const float* __restrict__ b2,
                                                  float* __restrict__ out) {
  const int tid = threadIdx.x;
  __shared__ alignas(16) float lds_in[H_];
  f32x4 w[32];
#pragma unroll
  for (int r = 0; r < 32; ++r) w[r] = *(const f32x4*)(W + tid * H_ + 4 * r);
  const float bsum = b1[tid] + b2[tid];
  const int m0 = blockIdx.x * 16;

  auto src_row = [&](int m) -> const float* {
    int t = m >> 3, b = m & 7;
    int tok = x[(b << 9) + t];          // x is [B,T]
    return emb + (size_t)tok * H_;
  };

  float stage = src_row(m0)[tid];
  for (int rr = 0; rr < 16; ++rr) {
    const int m = m0 + rr;
    lds_in[tid] = stage;
    __syncthreads();
    if (rr + 1 < 16) stage = src_row(m0 + rr + 1)[tid];
    f32x4 acc4 = {0.f, 0.f, 0.f, 0.f};
#pragma unroll
    for (int r = 0; r < 32; ++r) {
      f32x4 hv = *(const f32x4*)(lds_in + 4 * r);
      acc4 = __builtin_elementwise_fma(hv, w[r], acc4);
    }
    out[m * H_ + tid] = hsum4(acc4) + bsum;
    __syncthreads();
  }
}

// ---------------- mega kernel v3 ----------------
// grid 768 x 256 threads, LDS 33808 (3-4 blocks/CU possible), waves_per_eu(2)
// => 256-VGPR budget, no spill (scan needs ~132). Blocks 0-2 = the round-9
// proven 3-stage scan pipeline (1 CU each, other resident blocks keep the
// clock up). Blocks 3..767 = GEMM workers pulling tiles from an atomic
// counter (self-balancing), gated on prog2, reading pre-converted bf16 fcW.
__global__ __launch_bounds__(256) __attribute__((amdgpu_waves_per_eu(2)))
void mega3(const float* __restrict__ pre0,
           const float* __restrict__ W_hh0,
           const float* __restrict__ W_ih1,
           const float* __restrict__ W_hh1,
           const float* __restrict__ b_ih1,
           const float* __restrict__ b_hh1,
           unsigned short* __restrict__ h0g,
           float* __restrict__ pih_raw,
           unsigned short* __restrict__ h1b,
           unsigned int* __restrict__ prog0,
           unsigned int* __restrict__ prog1,
           unsigned int* __restrict__ prog2,
           unsigned int* __restrict__ tile_ctr,
           const unsigned short* __restrict__ fcWb,
           const float* __restrict__ fc_b,
           float* __restrict__ out) {
  __shared__ alignas(16) char smem[33808];   // 32K W-tile | [128][66] transpose; +tile slot
  const int bid = blockIdx.x;
  const int tid = threadIdx.x;
  const int wv = tid >> 6, lane = tid & 63;
  const f32x4 z4 = {0.f, 0.f, 0.f, 0.f};

  if (bid >= 3) {
    // ================= gemm workers (dynamic tiles) =================
    const int l15 = lane & 15, lg = lane >> 4;
    int* tile_slot = (int*)(smem + 33792);
    int known = 0;
    for (;;) {
      if (tid == 0)
        *tile_slot = (int)__hip_atomic_fetch_add(tile_ctr, 1u, __ATOMIC_RELAXED,
                                                 __HIP_MEMORY_SCOPE_AGENT);
      __syncthreads();
      const int tile = *tile_slot;
      __syncthreads();
      if (tile >= NTILES) break;
      const int tb = tile / 2000, r = tile - tb * 2000;
      const int nt = r >> 3, bb = r & 7;
      const int t0 = tb << 7, v0 = nt << 7;

      // stage fcW tile (bf16, 32KB) swizzled
      const char* gW = (const char*)fcWb + (size_t)v0 * 256;
#pragma unroll
      for (int it = 0; it < 8; ++it) {
        int c = it * 256 + tid;
        i32x4 vw = *(const i32x4*)(gW + c * 16);
        *(i32x4*)(smem + swz(c >> 4, c & 15)) = vw;
      }
      // gate on h1 progress
      const int need = (tb + 1) * 128;
      if (tid == 0 && known < need) {
        unsigned int p;
        while ((int)(p = ld_flag_acq(prog2)) < need) __builtin_amdgcn_s_sleep(32);
        known = (int)p;
      }
      __syncthreads();

      f32x4 acc[8][2] = {};   // [vf][mf]
#pragma unroll
      for (int kk = 0; kk < 4; ++kk) {
        const int cc = kk * 4 + lg;
        s16x8 a[8], bfr[2];
#pragma unroll
        for (int vf = 0; vf < 8; ++vf)
          a[vf] = *(const s16x8*)(smem + swz(vf * 16 + l15, cc));
#pragma unroll
        for (int mf = 0; mf < 2; ++mf) {
          int trow = t0 + wv * 32 + mf * 16 + l15;
          bfr[mf] = *(const s16x8*)(h1b + (size_t)((trow << 3) + bb) * H_ + kk * 32 + lg * 8);
        }
#pragma unroll
        for (int vf = 0; vf < 8; ++vf)
#pragma unroll
          for (int mf = 0; mf < 2; ++mf)
            acc[vf][mf] = MFMA16(a[vf], bfr[mf], acc[vf][mf]);
      }
#pragma unroll
      for (int vf = 0; vf < 8; ++vf) {
        f32x4 bv = *(const f32x4*)(fc_b + v0 + vf * 16 + (lg << 2));
#pragma unroll
        for (int mf = 0; mf < 2; ++mf) acc[vf][mf] += bv;
      }

      float* tbf = (float*)smem;
#pragma unroll
      for (int p = 0; p < 2; ++p) {
        __syncthreads();
#pragma unroll
        for (int q = 0; q < 4; ++q) {
          const int vf = p * 4 + q;
#pragma unroll
          for (int mf = 0; mf < 2; ++mf)
            *(f32x4*)(tbf + (wv * 32 + mf * 16 + l15) * 66 + q * 16 + lg * 4) = acc[vf][mf];
        }
        __syncthreads();
#pragma unroll
        for (int it = 0; it < 8; ++it) {
          int row = it * 16 + (tid >> 4);
          int col = (tid & 15) * 4;
          f32x4 val = *(const f32x4*)(tbf + row * 66 + col);
          const size_t off = (size_t)((bb << 9) + t0 + row) * V_ + v0 + p * 64 + col;
          __builtin_nontemporal_store(val, (f32x4*)(out + off));
        }
      }
      __syncthreads();   // before restaging W over tbf
    }
    return;
  }

  // ================= scan blocks (round-9 proven) =================
  typedef unsigned short (*HLP)[16][136];
  HLP hl = (HLP)smem;              // [2][16][136] bf16
  const int n = lane & 15, g = lane >> 4;
  const int nn = (n < 8) ? n : 7;
  const int w = wv;                // 4 waves, wave w owns M-tiles 2w, 2w+1
  const int m0 = w * 32;
  f32x4* pih_gf = (f32x4*)pih_raw;

  if (bid == 0) {
    // ---- stage 0: h0 recurrence ----
    for (int i = tid; i < 2 * 16 * 136; i += 256) ((unsigned short*)smem)[i] = 0;
    s16x8 whi[2][4], wlo[2][4];
#pragma unroll
    for (int hf = 0; hf < 2; ++hf)
#pragma unroll
      for (int kt = 0; kt < 4; ++kt) {
        const float* src = W_hh0 + (m0 + hf * 16 + n) * H_ + kt * 32 + g * 8;
        s16x8 hi, lo;
#pragma unroll
        for (int j = 0; j < 8; ++j) {
          float v = src[j];
          unsigned short hb = f2b(v);
          hi[j] = (short)hb;
          lo[j] = (short)f2b(v - __uint_as_float(((unsigned int)hb) << 16));
        }
        whi[hf][kt] = hi; wlo[hf][kt] = lo;
      }
    f32x4 fif[4][2];
#pragma unroll
    for (int k = 0; k < 4; ++k) {
      fif[k][0] = *(const f32x4*)(pre0 + ((k * 8 + nn) << 7) + m0 + g * 4);
      fif[k][1] = *(const f32x4*)(pre0 + ((k * 8 + nn) << 7) + m0 + 16 + g * 4);
    }
    __syncthreads();

    for (int s = 0; s < T_; ++s) {
      const int rd = (s + 1) & 1, wr = s & 1;
      const unsigned short* hb = &hl[rd][n][0];
      s16x8 b0 = *(const s16x8*)(hb + g * 8);
      s16x8 b1 = *(const s16x8*)(hb + 32 + g * 8);
      s16x8 b2 = *(const s16x8*)(hb + 64 + g * 8);
      s16x8 b3 = *(const s16x8*)(hb + 96 + g * 8);
      f32x4 hA = MFMA16(whi[0][0], b0, fif[s & 3][0]);
      f32x4 hB = MFMA16(whi[0][2], b2, z4);
      f32x4 lA = MFMA16(wlo[0][0], b0, z4);
      f32x4 lB = MFMA16(wlo[0][2], b2, z4);
      hA = MFMA16(whi[0][1], b1, hA);
      hB = MFMA16(whi[0][3], b3, hB);
      lA = MFMA16(wlo[0][1], b1, lA);
      lB = MFMA16(wlo[0][3], b3, lB);
      f32x4 hC = MFMA16(whi[1][0], b0, fif[s & 3][1]);
      f32x4 hD = MFMA16(whi[1][2], b2, z4);
      f32x4 lC = MFMA16(wlo[1][0], b0, z4);
      f32x4 lD = MFMA16(wlo[1][2], b2, z4);
      hC = MFMA16(whi[1][1], b1, hC);
      hD = MFMA16(whi[1][3], b3, hD);
      lC = MFMA16(wlo[1][1], b1, lC);
      lD = MFMA16(wlo[1][3], b3, lD);
      f32x4 v0 = tanh4((hA + hB) + (lA + lB));
      f32x4 v1 = tanh4((hC + hD) + (lC + lD));
      u32x2 o0 = pk4(v0), o1 = pk4(v1);
      *(u32x2*)&hl[wr][n][m0 + g * 4] = o0;
      *(u32x2*)&hl[wr][n][m0 + 16 + g * 4] = o1;
      if (n < 8) {
        *(u32x2*)(h0g + ((s * 8 + n) << 7) + m0 + g * 4) = o0;
        *(u32x2*)(h0g + ((s * 8 + n) << 7) + m0 + 16 + g * 4) = o1;
      }
      int sp = s + 4; if (sp > T_ - 1) sp = T_ - 1;
      fif[s & 3][0] = *(const f32x4*)(pre0 + ((sp * 8 + nn) << 7) + m0 + g * 4);
      fif[s & 3][1] = *(const f32x4*)(pre0 + ((sp * 8 + nn) << 7) + m0 + 16 + g * 4);
      if ((s & 7) == 7) {
        asm volatile("s_waitcnt vmcnt(0)" ::: "memory");
        lds_barrier();
        if (tid == 0) flag_add_rel(prog0, 8u);
      } else {
        lds_barrier();
      }
    }
  } else if (bid == 1) {
    // ---- stage 1: pih (hi-only), 4 independent waves, no barriers ----
    s16x8 whi[2][4];
#pragma unroll
    for (int hf = 0; hf < 2; ++hf)
#pragma unroll
      for (int kt = 0; kt < 4; ++kt) {
        const float* src = W_ih1 + (m0 + hf * 16 + n) * H_ + kt * 32 + g * 8;
        s16x8 hi;
#pragma unroll
        for (int j = 0; j < 8; ++j) hi[j] = (short)f2b(src[j]);
        whi[hf][kt] = hi;
      }
    const f32x4 bias0 = *(const f32x4*)(b_ih1 + m0 + g * 4) +
                        *(const f32x4*)(b_hh1 + m0 + g * 4);
    const f32x4 bias1 = *(const f32x4*)(b_ih1 + m0 + 16 + g * 4) +
                        *(const f32x4*)(b_hh1 + m0 + 16 + g * 4);

    while (ld_flag_acq(prog0) < 16u) __builtin_amdgcn_s_sleep(1);
    s16x8 fb[4][4];   // [slot][kt]
#pragma unroll
    for (int k = 0; k < 4; ++k)
#pragma unroll
      for (int kt = 0; kt < 4; ++kt)
        fb[k][kt] = *(const s16x8*)(h0g + ((k * 8 + nn) << 7) + kt * 32 + g * 8);

    for (int j = 0; j < T_; ++j) {
      if ((j & 7) == 0 && j > 0) {
        unsigned int req = (unsigned)(j + 16); if (req > 512u) req = 512u;
        while (ld_flag_acq(prog0) < req) __builtin_amdgcn_s_sleep(1);
      }
      const int sl = j & 3;
      f32x4 a0 = MFMA16(whi[0][0], fb[sl][0], bias0);
      f32x4 a1 = MFMA16(whi[0][2], fb[sl][2], z4);
      f32x4 c0 = MFMA16(whi[1][0], fb[sl][0], bias1);
      f32x4 c1 = MFMA16(whi[1][2], fb[sl][2], z4);
      a0 = MFMA16(whi[0][1], fb[sl][1], a0);
      a1 = MFMA16(whi[0][3], fb[sl][3], a1);
      c0 = MFMA16(whi[1][1], fb[sl][1], c0);
      c1 = MFMA16(whi[1][3], fb[sl][3], c1);
      f32x4 v0 = a0 + a1, v1 = c0 + c1;
      pih_gf[(size_t)(j * 8 + 2 * w) * 64 + n * 4 + g] = v0;
      pih_gf[(size_t)(j * 8 + 2 * w + 1) * 64 + n * 4 + g] = v1;
      int jp = j + 4;
      if (jp < T_) {
#pragma unroll
        for (int kt = 0; kt < 4; ++kt)
          fb[sl][kt] = *(const s16x8*)(h0g + ((jp * 8 + nn) << 7) + kt * 32 + g * 8);
      }
      if ((j & 7) == 7) {
        asm volatile("s_waitcnt vmcnt(0)" ::: "memory");
        if (lane == 0) flag_add_rel(prog1 + w, 8u);
      }
    }
  } else {
    // ---- stage 2: h1 recurrence ----
    for (int i = tid; i < 2 * 16 * 136; i += 256) ((unsigned short*)smem)[i] = 0;
    s16x8 whi[2][4], wlo[2][4];
#pragma unroll
    for (int hf = 0; hf < 2; ++hf)
#pragma unroll
      for (int kt = 0; kt < 4; ++kt) {
        const float* src = W_hh1 + (m0 + hf * 16 + n) * H_ + kt * 32 + g * 8;
        s16x8 hi, lo;
#pragma unroll
        for (int j = 0; j < 8; ++j) {
          float v = src[j];
          unsigned short hb = f2b(v);
          hi[j] = (short)hb;
          lo[j] = (short)f2b(v - __uint_as_float(((unsigned int)hb) << 16));
        }
        whi[hf][kt] = hi; wlo[hf][kt] = lo;
      }

    auto poll1 = [&](unsigned int req) {
      while (__any(ld_flag_acq(prog1 + (lane & 3)) < req)) __builtin_amdgcn_s_sleep(1);
    };
    poll1(16u);
    f32x4 pf[4][2];
#pragma unroll
    for (int k = 0; k < 4; ++k) {
      pf[k][0] = pih_gf[(size_t)(k * 8 + 2 * w) * 64 + n * 4 + g];
      pf[k][1] = pih_gf[(size_t)(k * 8 + 2 * w + 1) * 64 + n * 4 + g];
    }
    __syncthreads();

    for (int j = 0; j < T_; ++j) {
      if ((j & 7) == 0 && j > 0) {
        unsigned int req = (unsigned)(j + 16); if (req > 512u) req = 512u;
        poll1(req);
      }
      const int rd = (j + 1) & 1, wr = j & 1;
      const unsigned short* hb = &hl[rd][n][0];
      s16x8 b0 = *(const s16x8*)(hb + g * 8);
      s16x8 b1 = *(const s16x8*)(hb + 32 + g * 8);
      s16x8 b2 = *(const s16x8*)(hb + 64 + g * 8);
      s16x8 b3 = *(const s16x8*)(hb + 96 + g * 8);
      f32x4 hA = MFMA16(whi[0][0], b0, pf[j & 3][0]);
      f32x4 hB = MFMA16(whi[0][2], b2, z4);
      f32x4 lA = MFMA16(wlo[0][0], b0, z4);
      f32x4 lB = MFMA16(wlo[0][2], b2, z4);
      hA = MFMA16(whi[0][1], b1, hA);
      hB = MFMA16(whi[0][3], b3, hB);
      lA = MFMA16(wlo[0][1], b1, lA);
      lB = MFMA16(wlo[0][3], b3, lB);
      f32x4 hC = MFMA16(whi[1][0], b0, pf[j & 3][1]);
      f32x4 hD = MFMA16(whi[1][2], b2, z4);
      f32x4 lC = MFMA16(wlo[1][0], b0, z4);
      f32x4 lD = MFMA16(wlo[1][2], b2, z4);
      hC = MFMA16(whi[1][1], b1, hC);
      hD = MFMA16(whi[1][3], b3, hD);
      lC = MFMA16(wlo[1][1], b1, lC);
      lD = MFMA16(wlo[1][3], b3, lD);
      f32x4 v0 = tanh4((hA + hB) + (lA + lB));
      f32x4 v1 = tanh4((hC + hD) + (lC + lD));
      u32x2 o0 = pk4(v0), o1 = pk4(v1);
      *(u32x2*)&hl[wr][n][m0 + g * 4] = o0;
      *(u32x2*)&hl[wr][n][m0 + 16 + g * 4] = o1;
      if (n < 8) {
        *(u32x2*)(h1b + ((j * 8 + n) << 7) + m0 + g * 4) = o0;
        *(u32x2*)(h1b + ((j * 8 + n) << 7) + m0 + 16 + g * 4) = o1;
      }
      int jp = j + 4;
      if (jp < T_) {
        pf[j & 3][0] = pih_gf[(size_t)(jp * 8 + 2 * w) * 64 + n * 4 + g];
        pf[j & 3][1] = pih_gf[(size_t)(jp * 8 + 2 * w + 1) * 64 + n * 4 + g];
      }
      if ((j & 31) == 31) {
        asm volatile("s_waitcnt vmcnt(0)" ::: "memory");
        lds_barrier();
        if (tid == 0) flag_add_rel(prog2, 32u);
      } else {
        lds_barrier();
      }
    }
  }
}

extern "C" void kernel_launch(void* const* d_in, const int* in_sizes, int n_in,
                              void* d_out, int out_size, void* d_ws, size_t ws_size,
                              hipStream_t stream) {
  const int*   x     = (const int*)d_in[0];
  const float* emb   = (const float*)d_in[1];
  const float* W_ih0 = (const float*)d_in[2];
  const float* W_hh0 = (const float*)d_in[3];
  const float* b_ih0 = (const float*)d_in[4];
  const float* b_hh0 = (const float*)d_in[5];
  const float* W_ih1 = (const float*)d_in[6];
  const float* W_hh1 = (const float*)d_in[7];
  const float* b_ih1 = (const float*)d_in[8];
  const float* b_hh1 = (const float*)d_in[9];
  const float* fc_W  = (const float*)d_in[10];
  const float* fc_b  = (const float*)d_in[11];
  float* out = (float*)d_out;

  char* ws = (char*)d_ws;
  float*          pre0  = (float*)(ws + WS_PRE0);
  unsigned short* h1b   = (unsigned short*)(ws + WS_H1B);
  unsigned short* h0g   = (unsigned short*)(ws + WS_H0G);
  float*          pih   = (float*)(ws + WS_PIH);
  unsigned short* fcWb  = (unsigned short*)(ws + WS_FCWB);
  unsigned int*   prog0 = (unsigned int*)(ws + WS_FLAGS);
  unsigned int*   prog1 = (unsigned int*)(ws + WS_FLAGS + 256);
  unsigned int*   prog2 = (unsigned int*)(ws + WS_FLAGS + 512);
  unsigned int*   tctr  = (unsigned int*)(ws + WS_FLAGS + 768);

  hipMemsetAsync(ws + WS_FLAGS, 0, 4096, stream);
  convert_w_kernel<<<512, 256, 0, stream>>>(fc_W, fcWb, V_ * H_ / 4);
  pre_kernel<<<256, 128, 0, stream>>>(emb, x, W_ih0, b_ih0, b_hh0, pre0);
  mega3<<<GRID_ALL, 256, 0, stream>>>(pre0, W_hh0, W_ih1, W_hh1, b_ih1, b_hh1,
                                      h0g, pih, h1b, prog0, prog1, prog2,
                                      tctr, fcWb, fc_b, out);
}

// Round 11
// 3008.439 us; speedup vs baseline: 1.1735x; 1.1735x over previous
//
#include <hip/hip_runtime.h>
#include <hip/hip_bf16.h>

typedef __attribute__((ext_vector_type(4))) float f32x4;
typedef __attribute__((ext_vector_type(4))) int   i32x4;
typedef __attribute__((ext_vector_type(8))) short s16x8;
typedef __attribute__((ext_vector_type(4))) unsigned short u16x4;
typedef __attribute__((ext_vector_type(2))) unsigned int  u32x2;
typedef __attribute__((ext_vector_type(2))) unsigned long long u64x2;

#define T_ 512
#define B_ 8
#define H_ 128
#define V_ 32000

// ws layout (bytes)
#define WS_PRE0   0u          // [512][8][128] f32   2MB
#define WS_H1B    (2u<<20)    // [512][8][128] bf16  1MB
#define WS_FCWB   (3u<<20)    // [32000][128] bf16   8MB
#define WS_PIH    (11u<<20)   // [512][8][64] f32x4  4MB (stored as u64 pairs)
#define WS_FLAGS  (15u<<20)   // prog1 @+0, done @+512

#define GRID_SCAN 254         // 2 scan + 64 convert/spin + 188 spin

// round-to-nearest-even f32 -> bf16
__device__ __forceinline__ unsigned short f2b(float f) {
  unsigned int u = __float_as_uint(f);
  u = (u + 0x7FFFu + ((u >> 16) & 1u)) >> 16;
  return (unsigned short)u;
}

__device__ __forceinline__ float hsum4(f32x4 v) { return (v.x + v.y) + (v.z + v.w); }

__device__ __forceinline__ float tanh_fast(float x) {
  float e = __expf(2.f * x);
  return 1.f - 2.f * __builtin_amdgcn_rcpf(e + 1.f);
}

__device__ __forceinline__ f32x4 tanh4(f32x4 v) {
  f32x4 r;
  r.x = tanh_fast(v.x); r.y = tanh_fast(v.y);
  r.z = tanh_fast(v.z); r.w = tanh_fast(v.w);
  return r;
}

// pack 4 f32 -> 4 bf16 (2 dwords)
__device__ __forceinline__ u32x2 pk4(f32x4 v) {
  unsigned int a, b;
  asm("v_cvt_pk_bf16_f32 %0, %1, %2" : "=v"(a) : "v"(v.x), "v"(v.y));
  asm("v_cvt_pk_bf16_f32 %0, %1, %2" : "=v"(b) : "v"(v.z), "v"(v.w));
  u32x2 r; r.x = a; r.y = b; return r;
}

// barrier that does NOT drain vmcnt: LDS-only visibility + s_barrier.
__device__ __forceinline__ void lds_barrier() {
  asm volatile("s_waitcnt lgkmcnt(0)\n\ts_barrier" ::: "memory");
}

__device__ __forceinline__ void st_u64(unsigned long long* p, unsigned long long v) {
  __hip_atomic_store(p, v, __ATOMIC_RELAXED, __HIP_MEMORY_SCOPE_AGENT);
}
__device__ __forceinline__ unsigned long long ld_u64(const unsigned long long* p) {
  return __hip_atomic_load(p, __ATOMIC_RELAXED, __HIP_MEMORY_SCOPE_AGENT);
}
__device__ __forceinline__ unsigned int ld_flag_acq(const unsigned int* p) {
  return __hip_atomic_load(p, __ATOMIC_ACQUIRE, __HIP_MEMORY_SCOPE_AGENT);
}

#define MFMA16(A, B, C) __builtin_amdgcn_mfma_f32_16x16x32_bf16((A), (B), (C), 0, 0, 0)

// ---------------- pre0 = emb[x] @ W_ih0^T + b_ih0 + b_hh0 ----------------
__global__ __launch_bounds__(128) void pre_kernel(const float* __restrict__ emb,
                                                  const int* __restrict__ x,
                                                  const float* __restrict__ W,
                                                  const float* __restrict__ b1,
                                                  const float* __restrict__ b2,
                                                  float* __restrict__ out) {
  const int tid = threadIdx.x;
  __shared__ alignas(16) float lds_in[H_];
  f32x4 w[32];
#pragma unroll
  for (int r = 0; r < 32; ++r) w[r] = *(const f32x4*)(W + tid * H_ + 4 * r);
  const float bsum = b1[tid] + b2[tid];
  const int m0 = blockIdx.x * 16;

  auto src_row = [&](int m) -> const float* {
    int t = m >> 3, b = m & 7;
    int tok = x[(b << 9) + t];          // x is [B,T]
    return emb + (size_t)tok * H_;
  };

  float stage = src_row(m0)[tid];
  for (int rr = 0; rr < 16; ++rr) {
    const int m = m0 + rr;
    lds_in[tid] = stage;
    __syncthreads();
    if (rr + 1 < 16) stage = src_row(m0 + rr + 1)[tid];
    f32x4 acc4 = {0.f, 0.f, 0.f, 0.f};
#pragma unroll
    for (int r = 0; r < 32; ++r) {
      f32x4 hv = *(const f32x4*)(lds_in + 4 * r);
      acc4 = __builtin_elementwise_fma(hv, w[r], acc4);
    }
    out[m * H_ + tid] = hsum4(acc4) + bsum;
    __syncthreads();
  }
}

// ---------------- fused dual-layer scan (round-6 proven) + clock-hold spinners ----
// block 0: stage0 (h0 rec, W_hh0 hi/lo) waves 0-3 + stage1 (pih, hi-only) waves 4-7.
// block 1: stage2 (h1 rec, W_hh1 hi/lo), depth-4 pih FIFO; sets done flag at end.
// blocks 2..65: fc_W f32->bf16 convert, then VALU spin until done.
// blocks 66..253: pure VALU spin until done (keeps DVFS clock up; no memory
// traffic except one acquire poll per ~2us). Scan waves at s_setprio(1).
__global__ __launch_bounds__(512) __attribute__((amdgpu_waves_per_eu(2, 2)))
void fused_scan5(const float* __restrict__ pre0,
                 const float* __restrict__ W_hh0,
                 const float* __restrict__ W_ih1,
                 const float* __restrict__ W_hh1,
                 const float* __restrict__ b_ih1,
                 const float* __restrict__ b_hh1,
                 unsigned short* __restrict__ h1b,
                 unsigned long long* __restrict__ pih_g,
                 unsigned int* __restrict__ prog1,
                 unsigned int* __restrict__ done,
                 const float* __restrict__ fcw_src,
                 unsigned short* __restrict__ fcw_dst) {
  const int bid = blockIdx.x;
  const int tid = threadIdx.x;

  if (bid >= 2) {           // ---- converter / spinner blocks ----
    if (bid < 66) {
      int idx = (bid - 2) * 512 + tid;
      const int stride = 64 * 512;
      const int n4 = V_ * H_ / 4;
      for (int c = idx; c < n4; c += stride) {
        f32x4 v = ((const f32x4*)fcw_src)[c];
        u16x4 o; o.x = f2b(v.x); o.y = f2b(v.y); o.z = f2b(v.z); o.w = f2b(v.w);
        ((u16x4*)fcw_dst)[c] = o;
      }
    }
    // VALU spin to hold the clock up until the scan completes.
    float a = 1.0f + tid, b = 0.5f, c = 0.25f;
    for (;;) {
      if (ld_flag_acq(done) != 0u) break;
#pragma unroll
      for (int i = 0; i < 256; ++i) {
        a = __builtin_fmaf(a, b, c);
        b = __builtin_fmaf(b, c, a);
        c = __builtin_fmaf(c, a, b);
      }
      asm volatile("" :: "v"(a), "v"(b), "v"(c));   // keep live
      __builtin_amdgcn_s_sleep(8);
    }
    return;
  }

  __builtin_amdgcn_s_setprio(1);
  __shared__ unsigned short hl[2][16][136];
  const int wv = tid >> 6, lane = tid & 63;
  const int n = lane & 15, g = lane >> 4;
  const int nn = (n < 8) ? n : 7;
  for (int i = tid; i < 2 * 16 * 136; i += 512) ((unsigned short*)hl)[i] = 0;

  if (bid == 0) {
    // ================= stage 0 + stage 1 =================
    const bool is0 = wv < 4;
    const int w = wv & 3, m0 = w * 32;
    const float* Wm = is0 ? W_hh0 : W_ih1;
    s16x8 whi[2][4], wlo[2][4];
#pragma unroll
    for (int hf = 0; hf < 2; ++hf)
#pragma unroll
      for (int kt = 0; kt < 4; ++kt) {
        const float* src = Wm + (m0 + hf * 16 + n) * H_ + kt * 32 + g * 8;
        s16x8 hi, lo;
#pragma unroll
        for (int j = 0; j < 8; ++j) {
          float v = src[j];
          unsigned short hb = f2b(v);
          hi[j] = (short)hb;
          lo[j] = (short)f2b(v - __uint_as_float(((unsigned int)hb) << 16));
        }
        whi[hf][kt] = hi; wlo[hf][kt] = lo;
      }
    f32x4 c0b = {0.f,0.f,0.f,0.f}, c1b = {0.f,0.f,0.f,0.f};
    if (!is0) {
      c0b = *(const f32x4*)(b_ih1 + m0 + g * 4) + *(const f32x4*)(b_hh1 + m0 + g * 4);
      c1b = *(const f32x4*)(b_ih1 + m0 + 16 + g * 4) + *(const f32x4*)(b_hh1 + m0 + 16 + g * 4);
    }
    f32x4 fif[4][2];
    if (is0) {
#pragma unroll
      for (int k = 0; k < 4; ++k) {
        fif[k][0] = *(const f32x4*)(pre0 + (k * B_ + nn) * H_ + m0 + g * 4);
        fif[k][1] = *(const f32x4*)(pre0 + (k * B_ + nn) * H_ + m0 + 16 + g * 4);
      }
    }
    __syncthreads();

    for (int base = 0; base < T_; base += 4) {
#pragma unroll
      for (int k = 0; k < 4; ++k) {
        const int s = base + k;
        const int rd = (k + 1) & 1, wr = k & 1;
        const unsigned short* hb = &hl[rd][n][0];
        s16x8 b0 = *(const s16x8*)(hb + g * 8);
        s16x8 b1 = *(const s16x8*)(hb + 32 + g * 8);
        s16x8 b2 = *(const s16x8*)(hb + 64 + g * 8);
        s16x8 b3 = *(const s16x8*)(hb + 96 + g * 8);
        if (is0) {
          f32x4 aH0 = fif[k][0], aL0 = {0.f,0.f,0.f,0.f};
          f32x4 aH1 = fif[k][1], aL1 = {0.f,0.f,0.f,0.f};
          aH0 = MFMA16(whi[0][0], b0, aH0); aL0 = MFMA16(wlo[0][0], b0, aL0);
          aH0 = MFMA16(whi[0][1], b1, aH0); aL0 = MFMA16(wlo[0][1], b1, aL0);
          aH0 = MFMA16(whi[0][2], b2, aH0); aL0 = MFMA16(wlo[0][2], b2, aL0);
          aH0 = MFMA16(whi[0][3], b3, aH0); aL0 = MFMA16(wlo[0][3], b3, aL0);
          aH1 = MFMA16(whi[1][0], b0, aH1); aL1 = MFMA16(wlo[1][0], b0, aL1);
          aH1 = MFMA16(whi[1][1], b1, aH1); aL1 = MFMA16(wlo[1][1], b1, aL1);
          aH1 = MFMA16(whi[1][2], b2, aH1); aL1 = MFMA16(wlo[1][2], b2, aL1);
          aH1 = MFMA16(whi[1][3], b3, aH1); aL1 = MFMA16(wlo[1][3], b3, aL1);
          f32x4 v0 = tanh4(aH0 + aL0), v1 = tanh4(aH1 + aL1);
          *(u32x2*)&hl[wr][n][m0 + g * 4] = pk4(v0);
          *(u32x2*)&hl[wr][n][m0 + 16 + g * 4] = pk4(v1);
          int sp = s + 4; if (sp > T_ - 1) sp = T_ - 1;   // prefetch depth 4
          fif[k][0] = *(const f32x4*)(pre0 + (sp * B_ + nn) * H_ + m0 + g * 4);
          fif[k][1] = *(const f32x4*)(pre0 + (sp * B_ + nn) * H_ + m0 + 16 + g * 4);
        } else {
          if (k == 0 && base >= 4 && lane == 0)
            __hip_atomic_fetch_add(prog1, 4u, __ATOMIC_RELEASE, __HIP_MEMORY_SCOPE_AGENT);
          if (s >= 1) {
            f32x4 v0 = c0b, v1 = c1b;
            v0 = MFMA16(whi[0][0], b0, v0); v1 = MFMA16(whi[1][0], b0, v1);
            v0 = MFMA16(whi[0][1], b1, v0); v1 = MFMA16(whi[1][1], b1, v1);
            v0 = MFMA16(whi[0][2], b2, v0); v1 = MFMA16(whi[1][2], b2, v1);
            v0 = MFMA16(whi[0][3], b3, v0); v1 = MFMA16(whi[1][3], b3, v1);
            u64x2 u0 = __builtin_bit_cast(u64x2, v0);
            u64x2 u1 = __builtin_bit_cast(u64x2, v1);
            unsigned long long* p0 = pih_g + ((size_t)((s - 1) * 8 + 2 * w) * 64 + lane) * 2;
            st_u64(p0, u0.x); st_u64(p0 + 1, u0.y);
            unsigned long long* p1 = pih_g + ((size_t)((s - 1) * 8 + 2 * w + 1) * 64 + lane) * 2;
            st_u64(p1, u1.x); st_u64(p1 + 1, u1.y);
          }
        }
        lds_barrier();
      }
    }
    // tail region s = 512: stage1 computes pih[511], final release
    if (!is0) {
      const unsigned short* hb = &hl[1][n][0];   // written at region 511
      s16x8 b0 = *(const s16x8*)(hb + g * 8);
      s16x8 b1 = *(const s16x8*)(hb + 32 + g * 8);
      s16x8 b2 = *(const s16x8*)(hb + 64 + g * 8);
      s16x8 b3 = *(const s16x8*)(hb + 96 + g * 8);
      f32x4 v0 = c0b, v1 = c1b;
      v0 = MFMA16(whi[0][0], b0, v0); v1 = MFMA16(whi[1][0], b0, v1);
      v0 = MFMA16(whi[0][1], b1, v0); v1 = MFMA16(whi[1][1], b1, v1);
      v0 = MFMA16(whi[0][2], b2, v0); v1 = MFMA16(whi[1][2], b2, v1);
      v0 = MFMA16(whi[0][3], b3, v0); v1 = MFMA16(whi[1][3], b3, v1);
      u64x2 u0 = __builtin_bit_cast(u64x2, v0);
      u64x2 u1 = __builtin_bit_cast(u64x2, v1);
      unsigned long long* p0 = pih_g + ((size_t)(511 * 8 + 2 * w) * 64 + lane) * 2;
      st_u64(p0, u0.x); st_u64(p0 + 1, u0.y);
      unsigned long long* p1 = pih_g + ((size_t)(511 * 8 + 2 * w + 1) * 64 + lane) * 2;
      st_u64(p1, u1.x); st_u64(p1 + 1, u1.y);
      if (lane == 0)
        __hip_atomic_fetch_add(prog1, 16u, __ATOMIC_RELEASE, __HIP_MEMORY_SCOPE_AGENT);
    }
  } else {
    // ================= stage 2 =================
    const int m0 = wv * 16;    // 8 waves, 1 M-tile each
    s16x8 whi[4], wlo[4];
#pragma unroll
    for (int kt = 0; kt < 4; ++kt) {
      const float* src = W_hh1 + (m0 + n) * H_ + kt * 32 + g * 8;
      s16x8 hi, lo;
#pragma unroll
      for (int j = 0; j < 8; ++j) {
        float v = src[j];
        unsigned short hb = f2b(v);
        hi[j] = (short)hb;
        lo[j] = (short)f2b(v - __uint_as_float(((unsigned int)hb) << 16));
      }
      whi[kt] = hi; wlo[kt] = lo;
    }
    __syncthreads();

    auto ld_pih = [&](int step) -> f32x4 {
      const unsigned long long* p = pih_g + ((size_t)(step * 8 + wv) * 64 + lane) * 2;
      u64x2 u; u.x = ld_u64(p); u.y = ld_u64(p + 1);
      return __builtin_bit_cast(f32x4, u);
    };
    // prefill: need pih[0..3] => prog1 >= 20
    while (ld_flag_acq(prog1) < 20u) __builtin_amdgcn_s_sleep(2);
    f32x4 fif[4];
#pragma unroll
    for (int k = 0; k < 4; ++k) fif[k] = ld_pih(k);

    for (int base = 0; base < T_; base += 4) {
      if (base + 4 < T_) {
        const unsigned int t = 4u * (unsigned)(base + 9);
        while (ld_flag_acq(prog1) < t) __builtin_amdgcn_s_sleep(2);
      }
#pragma unroll
      for (int k = 0; k < 4; ++k) {
        const int j = base + k;
        const int rd = (k + 1) & 1, wr = k & 1;
        const unsigned short* hb = &hl[rd][n][0];
        s16x8 b0 = *(const s16x8*)(hb + g * 8);
        s16x8 b1 = *(const s16x8*)(hb + 32 + g * 8);
        s16x8 b2 = *(const s16x8*)(hb + 64 + g * 8);
        s16x8 b3 = *(const s16x8*)(hb + 96 + g * 8);
        f32x4 aH = fif[k], aL = {0.f,0.f,0.f,0.f};
        aH = MFMA16(whi[0], b0, aH); aL = MFMA16(wlo[0], b0, aL);
        aH = MFMA16(whi[1], b1, aH); aL = MFMA16(wlo[1], b1, aL);
        aH = MFMA16(whi[2], b2, aH); aL = MFMA16(wlo[2], b2, aL);
        aH = MFMA16(whi[3], b3, aH); aL = MFMA16(wlo[3], b3, aL);
        f32x4 v = tanh4(aH + aL);
        u32x2 o = pk4(v);
        *(u32x2*)&hl[wr][n][m0 + g * 4] = o;
        if (n < 8) *(u32x2*)(h1b + ((j * B_ + n) << 7) + m0 + g * 4) = o;
        if (j + 4 < T_) fif[k] = ld_pih(j + 4);
        lds_barrier();
      }
    }
    asm volatile("s_waitcnt vmcnt(0)" ::: "memory");
    __syncthreads();
    if (tid == 0)
      __hip_atomic_fetch_add(done, 1u, __ATOMIC_RELEASE, __HIP_MEMORY_SCOPE_AGENT);
  }
}

// ---------------- logits = h1 @ fc_W^T + fc_b (bf16 MFMA, round-6 gemm5) ----
__device__ __forceinline__ int swz(int row, int cc) {
  return row * 256 + ((cc ^ (row & 7)) << 4);
}

__global__ __launch_bounds__(256) void final_gemm5(const unsigned short* __restrict__ fcWb,
                                                   const unsigned short* __restrict__ h1b,
                                                   const float* __restrict__ bias,
                                                   float* __restrict__ out) {
  const int bid = blockIdx.x;
  const int x   = bid & 7;
  const int jb  = bid >> 3;
  const int mt  = jb & 31;
  const int ntl = jb >> 5;
  const int nt  = x * 32 + ntl;
  if (nt >= 250) return;

  __shared__ alignas(16) char smem[33792];   // W-stage 32KB | f32[128][66] transpose
  const int tid = threadIdx.x;
  const int bb = mt >> 2, tb = mt & 3;
  const int t0 = tb << 7;
  const int v0 = nt << 7;
  const int lane = tid & 63, wvv = tid >> 6;

  const char* gW = (const char*)fcWb + (size_t)v0 * 256;
#pragma unroll
  for (int it = 0; it < 8; ++it) {
    int cidx = it * 256 + tid;
    i32x4 vw = *(const i32x4*)(gW + cidx * 16);
    *(i32x4*)(smem + swz(cidx >> 4, cidx & 15)) = vw;
  }
  __syncthreads();

  const int l15 = lane & 15, lg = lane >> 4;
  f32x4 acc[8][2] = {};   // [vf][mf]
#pragma unroll
  for (int kk = 0; kk < 4; ++kk) {
    const int cc = kk * 4 + lg;
    s16x8 a[8], bfr[2];
#pragma unroll
    for (int vf = 0; vf < 8; ++vf)
      a[vf] = *(const s16x8*)(smem + swz(vf * 16 + l15, cc));
#pragma unroll
    for (int mf = 0; mf < 2; ++mf) {
      int trow = t0 + wvv * 32 + mf * 16 + l15;
      bfr[mf] = *(const s16x8*)(h1b + (size_t)((trow << 3) + bb) * H_ + kk * 32 + lg * 8);
    }
#pragma unroll
    for (int vf = 0; vf < 8; ++vf)
#pragma unroll
      for (int mf = 0; mf < 2; ++mf)
        acc[vf][mf] = MFMA16(a[vf], bfr[mf], acc[vf][mf]);
  }

#pragma unroll
  for (int vf = 0; vf < 8; ++vf) {
    f32x4 bv = *(const f32x4*)(bias + v0 + vf * 16 + (lg << 2));
#pragma unroll
    for (int mf = 0; mf < 2; ++mf) acc[vf][mf] += bv;
  }

  float* tbf = (float*)smem;
#pragma unroll
  for (int p = 0; p < 2; ++p) {
    __syncthreads();
#pragma unroll
    for (int q = 0; q < 4; ++q) {
      const int vf = p * 4 + q;
#pragma unroll
      for (int mf = 0; mf < 2; ++mf) {
        int t = wvv * 32 + mf * 16 + l15;
        int vl = q * 16 + lg * 4;
        *(f32x4*)(tbf + t * 66 + vl) = acc[vf][mf];
      }
    }
    __syncthreads();
#pragma unroll
    for (int it = 0; it < 8; ++it) {
      int row = it * 16 + (tid >> 4);
      int col = (tid & 15) * 4;
      f32x4 val = *(const f32x4*)(tbf + row * 66 + col);
      const size_t off = (size_t)((bb << 9) + t0 + row) * V_ + v0 + p * 64 + col;
      __builtin_nontemporal_store(val, (f32x4*)(out + off));
    }
  }
}

extern "C" void kernel_launch(void* const* d_in, const int* in_sizes, int n_in,
                              void* d_out, int out_size, void* d_ws, size_t ws_size,
                              hipStream_t stream) {
  const int*   x     = (const int*)d_in[0];
  const float* emb   = (const float*)d_in[1];
  const float* W_ih0 = (const float*)d_in[2];
  const float* W_hh0 = (const float*)d_in[3];
  const float* b_ih0 = (const float*)d_in[4];
  const float* b_hh0 = (const float*)d_in[5];
  const float* W_ih1 = (const float*)d_in[6];
  const float* W_hh1 = (const float*)d_in[7];
  const float* b_ih1 = (const float*)d_in[8];
  const float* b_hh1 = (const float*)d_in[9];
  const float* fc_W  = (const float*)d_in[10];
  const float* fc_b  = (const float*)d_in[11];
  float* out = (float*)d_out;

  char* ws = (char*)d_ws;
  float*              pre0  = (float*)(ws + WS_PRE0);
  unsigned short*     h1b   = (unsigned short*)(ws + WS_H1B);
  unsigned short*     fcWb  = (unsigned short*)(ws + WS_FCWB);
  unsigned long long* pih_g = (unsigned long long*)(ws + WS_PIH);
  unsigned int*       prog1 = (unsigned int*)(ws + WS_FLAGS);
  unsigned int*       done  = (unsigned int*)(ws + WS_FLAGS + 512);

  hipMemsetAsync(ws + WS_FLAGS, 0, 4096, stream);
  pre_kernel<<<256, 128, 0, stream>>>(emb, x, W_ih0, b_ih0, b_hh0, pre0);
  fused_scan5<<<GRID_SCAN, 512, 0, stream>>>(pre0, W_hh0, W_ih1, W_hh1, b_ih1, b_hh1,
                                             h1b, pih_g, prog1, done, fc_W, fcWb);
  final_gemm5<<<8192, 256, 0, stream>>>(fcWb, h1b, fc_b, out);
}

// Round 12
// 475.431 us; speedup vs baseline: 7.4258x; 6.3278x over previous
//
#include <hip/hip_runtime.h>
#include <hip/hip_bf16.h>

typedef __attribute__((ext_vector_type(4))) float f32x4;
typedef __attribute__((ext_vector_type(4))) int   i32x4;
typedef __attribute__((ext_vector_type(8))) short s16x8;
typedef __attribute__((ext_vector_type(4))) unsigned short u16x4;
typedef __attribute__((ext_vector_type(2))) unsigned int  u32x2;
typedef __attribute__((ext_vector_type(2))) unsigned long long u64x2;

#define T_ 512
#define B_ 8
#define H_ 128
#define V_ 32000

// ws layout (bytes)
#define WS_PRE0   0u          // [512][8][128] f32   2MB
#define WS_H1B    (2u<<20)    // [512][8][128] bf16  1MB
#define WS_FCWB   (3u<<20)    // [32000][128] bf16   8MB
#define WS_PIH    (11u<<20)   // [512][8][64] f32x4  4MB (stored as u64 pairs)
#define WS_FLAGS  (15u<<20)   // prog1 @+0

#define GRID_SCAN 254         // 2 scan + 64 convert+spin + 188 spin
#define SPIN_TICKS 20000ull   // 200 us at 100 MHz RTC (s_memrealtime)
#define SPIN_MAX_BURSTS 100   // safety bound if RTC freq assumption is wrong

// round-to-nearest-even f32 -> bf16
__device__ __forceinline__ unsigned short f2b(float f) {
  unsigned int u = __float_as_uint(f);
  u = (u + 0x7FFFu + ((u >> 16) & 1u)) >> 16;
  return (unsigned short)u;
}

__device__ __forceinline__ float hsum4(f32x4 v) { return (v.x + v.y) + (v.z + v.w); }

__device__ __forceinline__ float tanh_fast(float x) {
  float e = __expf(2.f * x);
  return 1.f - 2.f * __builtin_amdgcn_rcpf(e + 1.f);
}

__device__ __forceinline__ f32x4 tanh4(f32x4 v) {
  f32x4 r;
  r.x = tanh_fast(v.x); r.y = tanh_fast(v.y);
  r.z = tanh_fast(v.z); r.w = tanh_fast(v.w);
  return r;
}

// pack 4 f32 -> 4 bf16 (2 dwords)
__device__ __forceinline__ u32x2 pk4(f32x4 v) {
  unsigned int a, b;
  asm("v_cvt_pk_bf16_f32 %0, %1, %2" : "=v"(a) : "v"(v.x), "v"(v.y));
  asm("v_cvt_pk_bf16_f32 %0, %1, %2" : "=v"(b) : "v"(v.z), "v"(v.w));
  u32x2 r; r.x = a; r.y = b; return r;
}

// barrier that does NOT drain vmcnt: LDS-only visibility + s_barrier.
__device__ __forceinline__ void lds_barrier() {
  asm volatile("s_waitcnt lgkmcnt(0)\n\ts_barrier" ::: "memory");
}

__device__ __forceinline__ void st_u64(unsigned long long* p, unsigned long long v) {
  __hip_atomic_store(p, v, __ATOMIC_RELAXED, __HIP_MEMORY_SCOPE_AGENT);
}
__device__ __forceinline__ unsigned long long ld_u64(const unsigned long long* p) {
  return __hip_atomic_load(p, __ATOMIC_RELAXED, __HIP_MEMORY_SCOPE_AGENT);
}
__device__ __forceinline__ unsigned int ld_flag_acq(const unsigned int* p) {
  return __hip_atomic_load(p, __ATOMIC_ACQUIRE, __HIP_MEMORY_SCOPE_AGENT);
}

#define MFMA16(A, B, C) __builtin_amdgcn_mfma_f32_16x16x32_bf16((A), (B), (C), 0, 0, 0)

// ---------------- pre0 = emb[x] @ W_ih0^T + b_ih0 + b_hh0 ----------------
__global__ __launch_bounds__(128) void pre_kernel(const float* __restrict__ emb,
                                                  const int* __restrict__ x,
                                                  const float* __restrict__ W,
                                                  const float* __restrict__ b1,
                                                  const float* __restrict__ b2,
                                                  float* __restrict__ out) {
  const int tid = threadIdx.x;
  __shared__ alignas(16) float lds_in[H_];
  f32x4 w[32];
#pragma unroll
  for (int r = 0; r < 32; ++r) w[r] = *(const f32x4*)(W + tid * H_ + 4 * r);
  const float bsum = b1[tid] + b2[tid];
  const int m0 = blockIdx.x * 16;

  auto src_row = [&](int m) -> const float* {
    int t = m >> 3, b = m & 7;
    int tok = x[(b << 9) + t];          // x is [B,T]
    return emb + (size_t)tok * H_;
  };

  float stage = src_row(m0)[tid];
  for (int rr = 0; rr < 16; ++rr) {
    const int m = m0 + rr;
    lds_in[tid] = stage;
    __syncthreads();
    if (rr + 1 < 16) stage = src_row(m0 + rr + 1)[tid];
    f32x4 acc4 = {0.f, 0.f, 0.f, 0.f};
#pragma unroll
    for (int r = 0; r < 32; ++r) {
      f32x4 hv = *(const f32x4*)(lds_in + 4 * r);
      acc4 = __builtin_elementwise_fma(hv, w[r], acc4);
    }
    out[m * H_ + tid] = hsum4(acc4) + bsum;
    __syncthreads();
  }
}

// ---------------- fused dual-layer scan (round-6 verbatim) + ZERO-MEMORY spinners ----
// block 0: stage0 (h0 rec, W_hh0 hi/lo) waves 0-3 + stage1 (pih, hi-only) waves 4-7.
// block 1: stage2 (h1 rec, W_hh1 hi/lo), depth-4 pih FIFO via prog1 handshake.
// blocks 2..65: fc_W f32->bf16 convert, then timed register-only spin.
// blocks 66..253: timed register-only spin (dependent FMA bursts, exit on
// s_memrealtime >= 200us or burst cap). NO loads/stores/atomics in the spin —
// the DVFS A/B is clean: spinners hold clock, cannot touch the scan's memory path.
__global__ __launch_bounds__(512) __attribute__((amdgpu_waves_per_eu(2, 2)))
void fused_scan5(const float* __restrict__ pre0,
                 const float* __restrict__ W_hh0,
                 const float* __restrict__ W_ih1,
                 const float* __restrict__ W_hh1,
                 const float* __restrict__ b_ih1,
                 const float* __restrict__ b_hh1,
                 unsigned short* __restrict__ h1b,
                 unsigned long long* __restrict__ pih_g,
                 unsigned int* __restrict__ prog1,
                 const float* __restrict__ fcw_src,
                 unsigned short* __restrict__ fcw_dst) {
  const int bid = blockIdx.x;
  const int tid = threadIdx.x;

  if (bid >= 2) {           // ---- converter / spinner blocks ----
    if (bid < 66) {
      int idx = (bid - 2) * 512 + tid;
      const int stride = 64 * 512;
      const int n4 = V_ * H_ / 4;
      for (int c = idx; c < n4; c += stride) {
        f32x4 v = ((const f32x4*)fcw_src)[c];
        u16x4 o; o.x = f2b(v.x); o.y = f2b(v.y); o.z = f2b(v.z); o.w = f2b(v.w);
        ((u16x4*)fcw_dst)[c] = o;
      }
    }
    // Register-only timed spin: hold DVFS clock for the scan's duration.
    const unsigned long long t0 = __builtin_amdgcn_s_memrealtime();
    float a = 1.0f + (float)tid * 1e-6f, b = 0.999f, c = 1e-4f;
    for (int burst = 0; burst < SPIN_MAX_BURSTS; ++burst) {
#pragma unroll 64
      for (int i = 0; i < 512; ++i) {
        a = __builtin_fmaf(a, b, c);
        b = __builtin_fmaf(b, c, a);
        c = __builtin_fmaf(c, a, b);
      }
      asm volatile("" :: "v"(a), "v"(b), "v"(c));   // keep live, no memory
      if (__builtin_amdgcn_s_memrealtime() - t0 >= SPIN_TICKS) break;
    }
    return;
  }

  __shared__ unsigned short hl[2][16][136];
  const int wv = tid >> 6, lane = tid & 63;
  const int n = lane & 15, g = lane >> 4;
  const int nn = (n < 8) ? n : 7;
  for (int i = tid; i < 2 * 16 * 136; i += 512) ((unsigned short*)hl)[i] = 0;

  if (bid == 0) {
    // ================= stage 0 + stage 1 =================
    const bool is0 = wv < 4;
    const int w = wv & 3, m0 = w * 32;
    const float* Wm = is0 ? W_hh0 : W_ih1;
    s16x8 whi[2][4], wlo[2][4];
#pragma unroll
    for (int hf = 0; hf < 2; ++hf)
#pragma unroll
      for (int kt = 0; kt < 4; ++kt) {
        const float* src = Wm + (m0 + hf * 16 + n) * H_ + kt * 32 + g * 8;
        s16x8 hi, lo;
#pragma unroll
        for (int j = 0; j < 8; ++j) {
          float v = src[j];
          unsigned short hb = f2b(v);
          hi[j] = (short)hb;
          lo[j] = (short)f2b(v - __uint_as_float(((unsigned int)hb) << 16));
        }
        whi[hf][kt] = hi; wlo[hf][kt] = lo;
      }
    f32x4 c0b = {0.f,0.f,0.f,0.f}, c1b = {0.f,0.f,0.f,0.f};
    if (!is0) {
      c0b = *(const f32x4*)(b_ih1 + m0 + g * 4) + *(const f32x4*)(b_hh1 + m0 + g * 4);
      c1b = *(const f32x4*)(b_ih1 + m0 + 16 + g * 4) + *(const f32x4*)(b_hh1 + m0 + 16 + g * 4);
    }
    f32x4 fif[4][2];
    if (is0) {
#pragma unroll
      for (int k = 0; k < 4; ++k) {
        fif[k][0] = *(const f32x4*)(pre0 + (k * B_ + nn) * H_ + m0 + g * 4);
        fif[k][1] = *(const f32x4*)(pre0 + (k * B_ + nn) * H_ + m0 + 16 + g * 4);
      }
    }
    __syncthreads();

    for (int base = 0; base < T_; base += 4) {
#pragma unroll
      for (int k = 0; k < 4; ++k) {
        const int s = base + k;
        const int rd = (k + 1) & 1, wr = k & 1;
        const unsigned short* hb = &hl[rd][n][0];
        s16x8 b0 = *(const s16x8*)(hb + g * 8);
        s16x8 b1 = *(const s16x8*)(hb + 32 + g * 8);
        s16x8 b2 = *(const s16x8*)(hb + 64 + g * 8);
        s16x8 b3 = *(const s16x8*)(hb + 96 + g * 8);
        if (is0) {
          f32x4 aH0 = fif[k][0], aL0 = {0.f,0.f,0.f,0.f};
          f32x4 aH1 = fif[k][1], aL1 = {0.f,0.f,0.f,0.f};
          aH0 = MFMA16(whi[0][0], b0, aH0); aL0 = MFMA16(wlo[0][0], b0, aL0);
          aH0 = MFMA16(whi[0][1], b1, aH0); aL0 = MFMA16(wlo[0][1], b1, aL0);
          aH0 = MFMA16(whi[0][2], b2, aH0); aL0 = MFMA16(wlo[0][2], b2, aL0);
          aH0 = MFMA16(whi[0][3], b3, aH0); aL0 = MFMA16(wlo[0][3], b3, aL0);
          aH1 = MFMA16(whi[1][0], b0, aH1); aL1 = MFMA16(wlo[1][0], b0, aL1);
          aH1 = MFMA16(whi[1][1], b1, aH1); aL1 = MFMA16(wlo[1][1], b1, aL1);
          aH1 = MFMA16(whi[1][2], b2, aH1); aL1 = MFMA16(wlo[1][2], b2, aL1);
          aH1 = MFMA16(whi[1][3], b3, aH1); aL1 = MFMA16(wlo[1][3], b3, aL1);
          f32x4 v0 = tanh4(aH0 + aL0), v1 = tanh4(aH1 + aL1);
          *(u32x2*)&hl[wr][n][m0 + g * 4] = pk4(v0);
          *(u32x2*)&hl[wr][n][m0 + 16 + g * 4] = pk4(v1);
          int sp = s + 4; if (sp > T_ - 1) sp = T_ - 1;   // prefetch depth 4
          fif[k][0] = *(const f32x4*)(pre0 + (sp * B_ + nn) * H_ + m0 + g * 4);
          fif[k][1] = *(const f32x4*)(pre0 + (sp * B_ + nn) * H_ + m0 + 16 + g * 4);
        } else {
          if (k == 0 && base >= 4 && lane == 0)
            __hip_atomic_fetch_add(prog1, 4u, __ATOMIC_RELEASE, __HIP_MEMORY_SCOPE_AGENT);
          if (s >= 1) {
            f32x4 v0 = c0b, v1 = c1b;
            v0 = MFMA16(whi[0][0], b0, v0); v1 = MFMA16(whi[1][0], b0, v1);
            v0 = MFMA16(whi[0][1], b1, v0); v1 = MFMA16(whi[1][1], b1, v1);
            v0 = MFMA16(whi[0][2], b2, v0); v1 = MFMA16(whi[1][2], b2, v1);
            v0 = MFMA16(whi[0][3], b3, v0); v1 = MFMA16(whi[1][3], b3, v1);
            u64x2 u0 = __builtin_bit_cast(u64x2, v0);
            u64x2 u1 = __builtin_bit_cast(u64x2, v1);
            unsigned long long* p0 = pih_g + ((size_t)((s - 1) * 8 + 2 * w) * 64 + lane) * 2;
            st_u64(p0, u0.x); st_u64(p0 + 1, u0.y);
            unsigned long long* p1 = pih_g + ((size_t)((s - 1) * 8 + 2 * w + 1) * 64 + lane) * 2;
            st_u64(p1, u1.x); st_u64(p1 + 1, u1.y);
          }
        }
        lds_barrier();
      }
    }
    // tail region s = 512: stage1 computes pih[511], final release
    if (!is0) {
      const unsigned short* hb = &hl[1][n][0];   // written at region 511
      s16x8 b0 = *(const s16x8*)(hb + g * 8);
      s16x8 b1 = *(const s16x8*)(hb + 32 + g * 8);
      s16x8 b2 = *(const s16x8*)(hb + 64 + g * 8);
      s16x8 b3 = *(const s16x8*)(hb + 96 + g * 8);
      f32x4 v0 = c0b, v1 = c1b;
      v0 = MFMA16(whi[0][0], b0, v0); v1 = MFMA16(whi[1][0], b0, v1);
      v0 = MFMA16(whi[0][1], b1, v0); v1 = MFMA16(whi[1][1], b1, v1);
      v0 = MFMA16(whi[0][2], b2, v0); v1 = MFMA16(whi[1][2], b2, v1);
      v0 = MFMA16(whi[0][3], b3, v0); v1 = MFMA16(whi[1][3], b3, v1);
      u64x2 u0 = __builtin_bit_cast(u64x2, v0);
      u64x2 u1 = __builtin_bit_cast(u64x2, v1);
      unsigned long long* p0 = pih_g + ((size_t)(511 * 8 + 2 * w) * 64 + lane) * 2;
      st_u64(p0, u0.x); st_u64(p0 + 1, u0.y);
      unsigned long long* p1 = pih_g + ((size_t)(511 * 8 + 2 * w + 1) * 64 + lane) * 2;
      st_u64(p1, u1.x); st_u64(p1 + 1, u1.y);
      if (lane == 0)
        __hip_atomic_fetch_add(prog1, 16u, __ATOMIC_RELEASE, __HIP_MEMORY_SCOPE_AGENT);
    }
  } else {
    // ================= stage 2 =================
    const int m0 = wv * 16;    // 8 waves, 1 M-tile each
    s16x8 whi[4], wlo[4];
#pragma unroll
    for (int kt = 0; kt < 4; ++kt) {
      const float* src = W_hh1 + (m0 + n) * H_ + kt * 32 + g * 8;
      s16x8 hi, lo;
#pragma unroll
      for (int j = 0; j < 8; ++j) {
        float v = src[j];
        unsigned short hb = f2b(v);
        hi[j] = (short)hb;
        lo[j] = (short)f2b(v - __uint_as_float(((unsigned int)hb) << 16));
      }
      whi[kt] = hi; wlo[kt] = lo;
    }
    __syncthreads();

    auto ld_pih = [&](int step) -> f32x4 {
      const unsigned long long* p = pih_g + ((size_t)(step * 8 + wv) * 64 + lane) * 2;
      u64x2 u; u.x = ld_u64(p); u.y = ld_u64(p + 1);
      return __builtin_bit_cast(f32x4, u);
    };
    // prefill: need pih[0..3] => prog1 >= 20
    while (ld_flag_acq(prog1) < 20u) __builtin_amdgcn_s_sleep(2);
    f32x4 fif[4];
#pragma unroll
    for (int k = 0; k < 4; ++k) fif[k] = ld_pih(k);

    for (int base = 0; base < T_; base += 4) {
      if (base + 4 < T_) {
        const unsigned int t = 4u * (unsigned)(base + 9);
        while (ld_flag_acq(prog1) < t) __builtin_amdgcn_s_sleep(2);
      }
#pragma unroll
      for (int k = 0; k < 4; ++k) {
        const int j = base + k;
        const int rd = (k + 1) & 1, wr = k & 1;
        const unsigned short* hb = &hl[rd][n][0];
        s16x8 b0 = *(const s16x8*)(hb + g * 8);
        s16x8 b1 = *(const s16x8*)(hb + 32 + g * 8);
        s16x8 b2 = *(const s16x8*)(hb + 64 + g * 8);
        s16x8 b3 = *(const s16x8*)(hb + 96 + g * 8);
        f32x4 aH = fif[k], aL = {0.f,0.f,0.f,0.f};
        aH = MFMA16(whi[0], b0, aH); aL = MFMA16(wlo[0], b0, aL);
        aH = MFMA16(whi[1], b1, aH); aL = MFMA16(wlo[1], b1, aL);
        aH = MFMA16(whi[2], b2, aH); aL = MFMA16(wlo[2], b2, aL);
        aH = MFMA16(whi[3], b3, aH); aL = MFMA16(wlo[3], b3, aL);
        f32x4 v = tanh4(aH + aL);
        u32x2 o = pk4(v);
        *(u32x2*)&hl[wr][n][m0 + g * 4] = o;
        if (n < 8) *(u32x2*)(h1b + ((j * B_ + n) << 7) + m0 + g * 4) = o;
        if (j + 4 < T_) fif[k] = ld_pih(j + 4);
        lds_barrier();
      }
    }
  }
}

// ---------------- logits = h1 @ fc_W^T + fc_b (bf16 MFMA, round-6 gemm5) ----
__device__ __forceinline__ int swz(int row, int cc) {
  return row * 256 + ((cc ^ (row & 7)) << 4);
}

__global__ __launch_bounds__(256) void final_gemm5(const unsigned short* __restrict__ fcWb,
                                                   const unsigned short* __restrict__ h1b,
                                                   const float* __restrict__ bias,
                                                   float* __restrict__ out) {
  const int bid = blockIdx.x;
  const int x   = bid & 7;
  const int jb  = bid >> 3;
  const int mt  = jb & 31;
  const int ntl = jb >> 5;
  const int nt  = x * 32 + ntl;
  if (nt >= 250) return;

  __shared__ alignas(16) char smem[33792];   // W-stage 32KB | f32[128][66] transpose
  const int tid = threadIdx.x;
  const int bb = mt >> 2, tb = mt & 3;
  const int t0 = tb << 7;
  const int v0 = nt << 7;
  const int lane = tid & 63, wvv = tid >> 6;

  const char* gW = (const char*)fcWb + (size_t)v0 * 256;
#pragma unroll
  for (int it = 0; it < 8; ++it) {
    int cidx = it * 256 + tid;
    i32x4 vw = *(const i32x4*)(gW + cidx * 16);
    *(i32x4*)(smem + swz(cidx >> 4, cidx & 15)) = vw;
  }
  __syncthreads();

  const int l15 = lane & 15, lg = lane >> 4;
  f32x4 acc[8][2] = {};   // [vf][mf]
#pragma unroll
  for (int kk = 0; kk < 4; ++kk) {
    const int cc = kk * 4 + lg;
    s16x8 a[8], bfr[2];
#pragma unroll
    for (int vf = 0; vf < 8; ++vf)
      a[vf] = *(const s16x8*)(smem + swz(vf * 16 + l15, cc));
#pragma unroll
    for (int mf = 0; mf < 2; ++mf) {
      int trow = t0 + wvv * 32 + mf * 16 + l15;
      bfr[mf] = *(const s16x8*)(h1b + (size_t)((trow << 3) + bb) * H_ + kk * 32 + lg * 8);
    }
#pragma unroll
    for (int vf = 0; vf < 8; ++vf)
#pragma unroll
      for (int mf = 0; mf < 2; ++mf)
        acc[vf][mf] = MFMA16(a[vf], bfr[mf], acc[vf][mf]);
  }

#pragma unroll
  for (int vf = 0; vf < 8; ++vf) {
    f32x4 bv = *(const f32x4*)(bias + v0 + vf * 16 + (lg << 2));
#pragma unroll
    for (int mf = 0; mf < 2; ++mf) acc[vf][mf] += bv;
  }

  float* tbf = (float*)smem;
#pragma unroll
  for (int p = 0; p < 2; ++p) {
    __syncthreads();
#pragma unroll
    for (int q = 0; q < 4; ++q) {
      const int vf = p * 4 + q;
#pragma unroll
      for (int mf = 0; mf < 2; ++mf) {
        int t = wvv * 32 + mf * 16 + l15;
        int vl = q * 16 + lg * 4;
        *(f32x4*)(tbf + t * 66 + vl) = acc[vf][mf];
      }
    }
    __syncthreads();
#pragma unroll
    for (int it = 0; it < 8; ++it) {
      int row = it * 16 + (tid >> 4);
      int col = (tid & 15) * 4;
      f32x4 val = *(const f32x4*)(tbf + row * 66 + col);
      const size_t off = (size_t)((bb << 9) + t0 + row) * V_ + v0 + p * 64 + col;
      __builtin_nontemporal_store(val, (f32x4*)(out + off));
    }
  }
}

extern "C" void kernel_launch(void* const* d_in, const int* in_sizes, int n_in,
                              void* d_out, int out_size, void* d_ws, size_t ws_size,
                              hipStream_t stream) {
  const int*   x     = (const int*)d_in[0];
  const float* emb   = (const float*)d_in[1];
  const float* W_ih0 = (const float*)d_in[2];
  const float* W_hh0 = (const float*)d_in[3];
  const float* b_ih0 = (const float*)d_in[4];
  const float* b_hh0 = (const float*)d_in[5];
  const float* W_ih1 = (const float*)d_in[6];
  const float* W_hh1 = (const float*)d_in[7];
  const float* b_ih1 = (const float*)d_in[8];
  const float* b_hh1 = (const float*)d_in[9];
  const float* fc_W  = (const float*)d_in[10];
  const float* fc_b  = (const float*)d_in[11];
  float* out = (float*)d_out;

  char* ws = (char*)d_ws;
  float*              pre0  = (float*)(ws + WS_PRE0);
  unsigned short*     h1b   = (unsigned short*)(ws + WS_H1B);
  unsigned short*     fcWb  = (unsigned short*)(ws + WS_FCWB);
  unsigned long long* pih_g = (unsigned long long*)(ws + WS_PIH);
  unsigned int*       prog1 = (unsigned int*)(ws + WS_FLAGS);

  hipMemsetAsync(ws + WS_FLAGS, 0, 4096, stream);
  pre_kernel<<<256, 128, 0, stream>>>(emb, x, W_ih0, b_ih0, b_hh0, pre0);
  fused_scan5<<<GRID_SCAN, 512, 0, stream>>>(pre0, W_hh0, W_ih1, W_hh1, b_ih1, b_hh1,
                                             h1b, pih_g, prog1, fc_W, fcWb);
  final_gemm5<<<8192, 256, 0, stream>>>(fcWb, h1b, fc_b, out);
}

// Round 13
// 445.562 us; speedup vs baseline: 7.9236x; 1.0670x over previous
//
#include <hip/hip_runtime.h>
#include <hip/hip_bf16.h>

typedef __attribute__((ext_vector_type(4))) float f32x4;
typedef __attribute__((ext_vector_type(4))) int   i32x4;
typedef __attribute__((ext_vector_type(8))) short s16x8;
typedef __attribute__((ext_vector_type(4))) unsigned short u16x4;
typedef __attribute__((ext_vector_type(2))) unsigned int  u32x2;
typedef __attribute__((ext_vector_type(2))) unsigned long long u64x2;

#define T_ 512
#define B_ 8
#define H_ 128
#define V_ 32000

// ws layout (bytes)
#define WS_PRE0   0u          // [512][8][128] f32   2MB
#define WS_H1B    (2u<<20)    // [512][8][128] bf16  1MB
#define WS_FCWB   (3u<<20)    // [32000][128] bf16   8MB
#define WS_PIH    (11u<<20)   // [512][8][64] f32x4  4MB (stored as u64 pairs)
#define WS_FLAGS  (15u<<20)   // prog1 @+0

#define GRID_SCAN 66          // 2 scan + 64 convert

// round-to-nearest-even f32 -> bf16
__device__ __forceinline__ unsigned short f2b(float f) {
  unsigned int u = __float_as_uint(f);
  u = (u + 0x7FFFu + ((u >> 16) & 1u)) >> 16;
  return (unsigned short)u;
}

__device__ __forceinline__ float hsum4(f32x4 v) { return (v.x + v.y) + (v.z + v.w); }

__device__ __forceinline__ float tanh_fast(float x) {
  float e = __expf(2.f * x);
  return 1.f - 2.f * __builtin_amdgcn_rcpf(e + 1.f);
}

__device__ __forceinline__ f32x4 tanh4(f32x4 v) {
  f32x4 r;
  r.x = tanh_fast(v.x); r.y = tanh_fast(v.y);
  r.z = tanh_fast(v.z); r.w = tanh_fast(v.w);
  return r;
}

// pack 4 f32 -> 4 bf16 (2 dwords)
__device__ __forceinline__ u32x2 pk4(f32x4 v) {
  unsigned int a, b;
  asm("v_cvt_pk_bf16_f32 %0, %1, %2" : "=v"(a) : "v"(v.x), "v"(v.y));
  asm("v_cvt_pk_bf16_f32 %0, %1, %2" : "=v"(b) : "v"(v.z), "v"(v.w));
  u32x2 r; r.x = a; r.y = b; return r;
}

// barrier that does NOT drain vmcnt: LDS-only visibility + s_barrier.
__device__ __forceinline__ void lds_barrier() {
  asm volatile("s_waitcnt lgkmcnt(0)\n\ts_barrier" ::: "memory");
}

__device__ __forceinline__ void st_u64(unsigned long long* p, unsigned long long v) {
  __hip_atomic_store(p, v, __ATOMIC_RELAXED, __HIP_MEMORY_SCOPE_AGENT);
}
__device__ __forceinline__ unsigned long long ld_u64(const unsigned long long* p) {
  return __hip_atomic_load(p, __ATOMIC_RELAXED, __HIP_MEMORY_SCOPE_AGENT);
}
__device__ __forceinline__ unsigned int ld_flag_acq(const unsigned int* p) {
  return __hip_atomic_load(p, __ATOMIC_ACQUIRE, __HIP_MEMORY_SCOPE_AGENT);
}

#define MFMA16(A, B, C) __builtin_amdgcn_mfma_f32_16x16x32_bf16((A), (B), (C), 0, 0, 0)

// ---------------- pre0 = emb[x] @ W_ih0^T + b_ih0 + b_hh0 ----------------
__global__ __launch_bounds__(128) void pre_kernel(const float* __restrict__ emb,
                                                  const int* __restrict__ x,
                                                  const float* __restrict__ W,
                                                  const float* __restrict__ b1,
                                                  const float* __restrict__ b2,
                                                  float* __restrict__ out) {
  const int tid = threadIdx.x;
  __shared__ alignas(16) float lds_in[H_];
  f32x4 w[32];
#pragma unroll
  for (int r = 0; r < 32; ++r) w[r] = *(const f32x4*)(W + tid * H_ + 4 * r);
  const float bsum = b1[tid] + b2[tid];
  const int m0 = blockIdx.x * 16;

  auto src_row = [&](int m) -> const float* {
    int t = m >> 3, b = m & 7;
    int tok = x[(b << 9) + t];          // x is [B,T]
    return emb + (size_t)tok * H_;
  };

  float stage = src_row(m0)[tid];
  for (int rr = 0; rr < 16; ++rr) {
    const int m = m0 + rr;
    lds_in[tid] = stage;
    __syncthreads();
    if (rr + 1 < 16) stage = src_row(m0 + rr + 1)[tid];
    f32x4 acc4 = {0.f, 0.f, 0.f, 0.f};
#pragma unroll
    for (int r = 0; r < 32; ++r) {
      f32x4 hv = *(const f32x4*)(lds_in + 4 * r);
      acc4 = __builtin_elementwise_fma(hv, w[r], acc4);
    }
    out[m * H_ + tid] = hsum4(acc4) + bsum;
    __syncthreads();
  }
}

// ---------------- fused dual-layer scan (round-6 structure, 2+2 MFMA chains) ----
// block 0: stage0 (h0 rec, W_hh0 hi/lo) waves 0-3 + stage1 (pih, hi-only) waves 4-7.
//   All MFMA K-chains restructured 4-deep -> 2+2 parallel (halves dep latency).
// block 1: stage2 (h1 rec, W_hh1 hi/lo), depth-8 pih FIFO, acquire-poll every
//   8 regions (was 4) -> half the poll overhead on the serial path.
// blocks 2..65: fc_W f32->bf16 convert (concurrent, off the critical path).
__global__ __launch_bounds__(512) __attribute__((amdgpu_waves_per_eu(2, 2)))
void fused_scan7(const float* __restrict__ pre0,
                 const float* __restrict__ W_hh0,
                 const float* __restrict__ W_ih1,
                 const float* __restrict__ W_hh1,
                 const float* __restrict__ b_ih1,
                 const float* __restrict__ b_hh1,
                 unsigned short* __restrict__ h1b,
                 unsigned long long* __restrict__ pih_g,
                 unsigned int* __restrict__ prog1,
                 const float* __restrict__ fcw_src,
                 unsigned short* __restrict__ fcw_dst) {
  const int bid = blockIdx.x;
  const int tid = threadIdx.x;

  if (bid >= 2) {           // ---- converter blocks ----
    int idx = (bid - 2) * 512 + tid;
    const int stride = 64 * 512;
    const int n4 = V_ * H_ / 4;
    for (int c = idx; c < n4; c += stride) {
      f32x4 v = ((const f32x4*)fcw_src)[c];
      u16x4 o; o.x = f2b(v.x); o.y = f2b(v.y); o.z = f2b(v.z); o.w = f2b(v.w);
      ((u16x4*)fcw_dst)[c] = o;
    }
    return;
  }

  __shared__ unsigned short hl[2][16][136];
  const int wv = tid >> 6, lane = tid & 63;
  const int n = lane & 15, g = lane >> 4;
  const int nn = (n < 8) ? n : 7;
  const f32x4 z4 = {0.f, 0.f, 0.f, 0.f};
  for (int i = tid; i < 2 * 16 * 136; i += 512) ((unsigned short*)hl)[i] = 0;

  if (bid == 0) {
    // ================= stage 0 + stage 1 =================
    const bool is0 = wv < 4;
    const int w = wv & 3, m0 = w * 32;
    const float* Wm = is0 ? W_hh0 : W_ih1;
    s16x8 whi[2][4], wlo[2][4];
#pragma unroll
    for (int hf = 0; hf < 2; ++hf)
#pragma unroll
      for (int kt = 0; kt < 4; ++kt) {
        const float* src = Wm + (m0 + hf * 16 + n) * H_ + kt * 32 + g * 8;
        s16x8 hi, lo;
#pragma unroll
        for (int j = 0; j < 8; ++j) {
          float v = src[j];
          unsigned short hb = f2b(v);
          hi[j] = (short)hb;
          lo[j] = (short)f2b(v - __uint_as_float(((unsigned int)hb) << 16));
        }
        whi[hf][kt] = hi; wlo[hf][kt] = lo;
      }
    f32x4 c0b = {0.f,0.f,0.f,0.f}, c1b = {0.f,0.f,0.f,0.f};
    if (!is0) {
      c0b = *(const f32x4*)(b_ih1 + m0 + g * 4) + *(const f32x4*)(b_hh1 + m0 + g * 4);
      c1b = *(const f32x4*)(b_ih1 + m0 + 16 + g * 4) + *(const f32x4*)(b_hh1 + m0 + 16 + g * 4);
    }
    f32x4 fif[4][2];
    if (is0) {
#pragma unroll
      for (int k = 0; k < 4; ++k) {
        fif[k][0] = *(const f32x4*)(pre0 + (k * B_ + nn) * H_ + m0 + g * 4);
        fif[k][1] = *(const f32x4*)(pre0 + (k * B_ + nn) * H_ + m0 + 16 + g * 4);
      }
    }
    __syncthreads();

    for (int base = 0; base < T_; base += 4) {
#pragma unroll
      for (int k = 0; k < 4; ++k) {
        const int s = base + k;
        const int rd = (k + 1) & 1, wr = k & 1;
        const unsigned short* hb = &hl[rd][n][0];
        s16x8 b0 = *(const s16x8*)(hb + g * 8);
        s16x8 b1 = *(const s16x8*)(hb + 32 + g * 8);
        s16x8 b2 = *(const s16x8*)(hb + 64 + g * 8);
        s16x8 b3 = *(const s16x8*)(hb + 96 + g * 8);
        if (is0) {
          // half 0: 4 parallel chains of depth 2
          f32x4 hAa = MFMA16(whi[0][0], b0, fif[k][0]);
          f32x4 hAb = MFMA16(whi[0][2], b2, z4);
          f32x4 lAa = MFMA16(wlo[0][0], b0, z4);
          f32x4 lAb = MFMA16(wlo[0][2], b2, z4);
          hAa = MFMA16(whi[0][1], b1, hAa);
          hAb = MFMA16(whi[0][3], b3, hAb);
          lAa = MFMA16(wlo[0][1], b1, lAa);
          lAb = MFMA16(wlo[0][3], b3, lAb);
          // half 1
          f32x4 hBa = MFMA16(whi[1][0], b0, fif[k][1]);
          f32x4 hBb = MFMA16(whi[1][2], b2, z4);
          f32x4 lBa = MFMA16(wlo[1][0], b0, z4);
          f32x4 lBb = MFMA16(wlo[1][2], b2, z4);
          hBa = MFMA16(whi[1][1], b1, hBa);
          hBb = MFMA16(whi[1][3], b3, hBb);
          lBa = MFMA16(wlo[1][1], b1, lBa);
          lBb = MFMA16(wlo[1][3], b3, lBb);
          f32x4 v0 = tanh4((hAa + hAb) + (lAa + lAb));
          f32x4 v1 = tanh4((hBa + hBb) + (lBa + lBb));
          *(u32x2*)&hl[wr][n][m0 + g * 4] = pk4(v0);
          *(u32x2*)&hl[wr][n][m0 + 16 + g * 4] = pk4(v1);
          int sp = s + 4; if (sp > T_ - 1) sp = T_ - 1;   // prefetch depth 4
          fif[k][0] = *(const f32x4*)(pre0 + (sp * B_ + nn) * H_ + m0 + g * 4);
          fif[k][1] = *(const f32x4*)(pre0 + (sp * B_ + nn) * H_ + m0 + 16 + g * 4);
        } else {
          if (k == 0 && base >= 4 && lane == 0)
            __hip_atomic_fetch_add(prog1, 4u, __ATOMIC_RELEASE, __HIP_MEMORY_SCOPE_AGENT);
          if (s >= 1) {
            f32x4 v0a = MFMA16(whi[0][0], b0, c0b);
            f32x4 v0bq = MFMA16(whi[0][2], b2, z4);
            f32x4 v1a = MFMA16(whi[1][0], b0, c1b);
            f32x4 v1bq = MFMA16(whi[1][2], b2, z4);
            v0a = MFMA16(whi[0][1], b1, v0a);
            v0bq = MFMA16(whi[0][3], b3, v0bq);
            v1a = MFMA16(whi[1][1], b1, v1a);
            v1bq = MFMA16(whi[1][3], b3, v1bq);
            f32x4 v0 = v0a + v0bq, v1 = v1a + v1bq;
            u64x2 u0 = __builtin_bit_cast(u64x2, v0);
            u64x2 u1 = __builtin_bit_cast(u64x2, v1);
            unsigned long long* p0 = pih_g + ((size_t)((s - 1) * 8 + 2 * w) * 64 + lane) * 2;
            st_u64(p0, u0.x); st_u64(p0 + 1, u0.y);
            unsigned long long* p1 = pih_g + ((size_t)((s - 1) * 8 + 2 * w + 1) * 64 + lane) * 2;
            st_u64(p1, u1.x); st_u64(p1 + 1, u1.y);
          }
        }
        lds_barrier();
      }
    }
    // tail region s = 512: stage1 computes pih[511], final release
    if (!is0) {
      const unsigned short* hb = &hl[1][n][0];   // written at region 511
      s16x8 b0 = *(const s16x8*)(hb + g * 8);
      s16x8 b1 = *(const s16x8*)(hb + 32 + g * 8);
      s16x8 b2 = *(const s16x8*)(hb + 64 + g * 8);
      s16x8 b3 = *(const s16x8*)(hb + 96 + g * 8);
      f32x4 v0 = c0b, v1 = c1b;
      v0 = MFMA16(whi[0][0], b0, v0); v1 = MFMA16(whi[1][0], b0, v1);
      v0 = MFMA16(whi[0][1], b1, v0); v1 = MFMA16(whi[1][1], b1, v1);
      v0 = MFMA16(whi[0][2], b2, v0); v1 = MFMA16(whi[1][2], b2, v1);
      v0 = MFMA16(whi[0][3], b3, v0); v1 = MFMA16(whi[1][3], b3, v1);
      u64x2 u0 = __builtin_bit_cast(u64x2, v0);
      u64x2 u1 = __builtin_bit_cast(u64x2, v1);
      unsigned long long* p0 = pih_g + ((size_t)(511 * 8 + 2 * w) * 64 + lane) * 2;
      st_u64(p0, u0.x); st_u64(p0 + 1, u0.y);
      unsigned long long* p1 = pih_g + ((size_t)(511 * 8 + 2 * w + 1) * 64 + lane) * 2;
      st_u64(p1, u1.x); st_u64(p1 + 1, u1.y);
      if (lane == 0)
        __hip_atomic_fetch_add(prog1, 16u, __ATOMIC_RELEASE, __HIP_MEMORY_SCOPE_AGENT);
    }
  } else {
    // ================= stage 2: depth-8 FIFO, poll every 8 =================
    const int m0 = wv * 16;    // 8 waves, 1 M-tile each
    s16x8 whi[4], wlo[4];
#pragma unroll
    for (int kt = 0; kt < 4; ++kt) {
      const float* src = W_hh1 + (m0 + n) * H_ + kt * 32 + g * 8;
      s16x8 hi, lo;
#pragma unroll
      for (int j = 0; j < 8; ++j) {
        float v = src[j];
        unsigned short hb = f2b(v);
        hi[j] = (short)hb;
        lo[j] = (short)f2b(v - __uint_as_float(((unsigned int)hb) << 16));
      }
      whi[kt] = hi; wlo[kt] = lo;
    }
    __syncthreads();

    auto ld_pih = [&](int step) -> f32x4 {
      const unsigned long long* p = pih_g + ((size_t)(step * 8 + wv) * 64 + lane) * 2;
      u64x2 u; u.x = ld_u64(p); u.y = ld_u64(p + 1);
      return __builtin_bit_cast(f32x4, u);
    };
    // prefill pih[0..7]: stored by producer step 8 -> prog1 >= 36 (slack incl.)
    while (ld_flag_acq(prog1) < 36u) __builtin_amdgcn_s_sleep(2);
    f32x4 fif[8];
#pragma unroll
    for (int k = 0; k < 8; ++k) fif[k] = ld_pih(k);

    for (int base = 0; base < T_; base += 8) {
      if (base + 8 < T_) {
        // loads this group reach pih[base+15] (store at step base+16) -> 4*(base+17)
        const unsigned int t = 4u * (unsigned)(base + 17);
        while (ld_flag_acq(prog1) < t) __builtin_amdgcn_s_sleep(2);
      }
#pragma unroll
      for (int k = 0; k < 8; ++k) {
        const int j = base + k;
        const int rd = (j + 1) & 1, wr = j & 1;
        const unsigned short* hb = &hl[rd][n][0];
        s16x8 b0 = *(const s16x8*)(hb + g * 8);
        s16x8 b1 = *(const s16x8*)(hb + 32 + g * 8);
        s16x8 b2 = *(const s16x8*)(hb + 64 + g * 8);
        s16x8 b3 = *(const s16x8*)(hb + 96 + g * 8);
        // 4 parallel chains of depth 2
        f32x4 aHa = MFMA16(whi[0], b0, fif[k]);
        f32x4 aHb = MFMA16(whi[2], b2, z4);
        f32x4 aLa = MFMA16(wlo[0], b0, z4);
        f32x4 aLb = MFMA16(wlo[2], b2, z4);
        aHa = MFMA16(whi[1], b1, aHa);
        aHb = MFMA16(whi[3], b3, aHb);
        aLa = MFMA16(wlo[1], b1, aLa);
        aLb = MFMA16(wlo[3], b3, aLb);
        f32x4 v = tanh4((aHa + aHb) + (aLa + aLb));
        u32x2 o = pk4(v);
        *(u32x2*)&hl[wr][n][m0 + g * 4] = o;
        if (n < 8) *(u32x2*)(h1b + ((j * B_ + n) << 7) + m0 + g * 4) = o;
        if (j + 8 < T_) fif[k] = ld_pih(j + 8);
        lds_barrier();
      }
    }
  }
}

// ---------------- logits = h1 @ fc_W^T + fc_b (bf16 MFMA, round-6 gemm5) ----
__device__ __forceinline__ int swz(int row, int cc) {
  return row * 256 + ((cc ^ (row & 7)) << 4);
}

__global__ __launch_bounds__(256) void final_gemm5(const unsigned short* __restrict__ fcWb,
                                                   const unsigned short* __restrict__ h1b,
                                                   const float* __restrict__ bias,
                                                   float* __restrict__ out) {
  const int bid = blockIdx.x;
  const int x   = bid & 7;
  const int jb  = bid >> 3;
  const int mt  = jb & 31;
  const int ntl = jb >> 5;
  const int nt  = x * 32 + ntl;
  if (nt >= 250) return;

  __shared__ alignas(16) char smem[33792];   // W-stage 32KB | f32[128][66] transpose
  const int tid = threadIdx.x;
  const int bb = mt >> 2, tb = mt & 3;
  const int t0 = tb << 7;
  const int v0 = nt << 7;
  const int lane = tid & 63, wvv = tid >> 6;

  const char* gW = (const char*)fcWb + (size_t)v0 * 256;
#pragma unroll
  for (int it = 0; it < 8; ++it) {
    int cidx = it * 256 + tid;
    i32x4 vw = *(const i32x4*)(gW + cidx * 16);
    *(i32x4*)(smem + swz(cidx >> 4, cidx & 15)) = vw;
  }
  __syncthreads();

  const int l15 = lane & 15, lg = lane >> 4;
  f32x4 acc[8][2] = {};   // [vf][mf]
#pragma unroll
  for (int kk = 0; kk < 4; ++kk) {
    const int cc = kk * 4 + lg;
    s16x8 a[8], bfr[2];
#pragma unroll
    for (int vf = 0; vf < 8; ++vf)
      a[vf] = *(const s16x8*)(smem + swz(vf * 16 + l15, cc));
#pragma unroll
    for (int mf = 0; mf < 2; ++mf) {
      int trow = t0 + wvv * 32 + mf * 16 + l15;
      bfr[mf] = *(const s16x8*)(h1b + (size_t)((trow << 3) + bb) * H_ + kk * 32 + lg * 8);
    }
#pragma unroll
    for (int vf = 0; vf < 8; ++vf)
#pragma unroll
      for (int mf = 0; mf < 2; ++mf)
        acc[vf][mf] = MFMA16(a[vf], bfr[mf], acc[vf][mf]);
  }

#pragma unroll
  for (int vf = 0; vf < 8; ++vf) {
    f32x4 bv = *(const f32x4*)(bias + v0 + vf * 16 + (lg << 2));
#pragma unroll
    for (int mf = 0; mf < 2; ++mf) acc[vf][mf] += bv;
  }

  float* tbf = (float*)smem;
#pragma unroll
  for (int p = 0; p < 2; ++p) {
    __syncthreads();
#pragma unroll
    for (int q = 0; q < 4; ++q) {
      const int vf = p * 4 + q;
#pragma unroll
      for (int mf = 0; mf < 2; ++mf) {
        int t = wvv * 32 + mf * 16 + l15;
        int vl = q * 16 + lg * 4;
        *(f32x4*)(tbf + t * 66 + vl) = acc[vf][mf];
      }
    }
    __syncthreads();
#pragma unroll
    for (int it = 0; it < 8; ++it) {
      int row = it * 16 + (tid >> 4);
      int col = (tid & 15) * 4;
      f32x4 val = *(const f32x4*)(tbf + row * 66 + col);
      const size_t off = (size_t)((bb << 9) + t0 + row) * V_ + v0 + p * 64 + col;
      __builtin_nontemporal_store(val, (f32x4*)(out + off));
    }
  }
}

extern "C" void kernel_launch(void* const* d_in, const int* in_sizes, int n_in,
                              void* d_out, int out_size, void* d_ws, size_t ws_size,
                              hipStream_t stream) {
  const int*   x     = (const int*)d_in[0];
  const float* emb   = (const float*)d_in[1];
  const float* W_ih0 = (const float*)d_in[2];
  const float* W_hh0 = (const float*)d_in[3];
  const float* b_ih0 = (const float*)d_in[4];
  const float* b_hh0 = (const float*)d_in[5];
  const float* W_ih1 = (const float*)d_in[6];
  const float* W_hh1 = (const float*)d_in[7];
  const float* b_ih1 = (const float*)d_in[8];
  const float* b_hh1 = (const float*)d_in[9];
  const float* fc_W  = (const float*)d_in[10];
  const float* fc_b  = (const float*)d_in[11];
  float* out = (float*)d_out;

  char* ws = (char*)d_ws;
  float*              pre0  = (float*)(ws + WS_PRE0);
  unsigned short*     h1b   = (unsigned short*)(ws + WS_H1B);
  unsigned short*     fcWb  = (unsigned short*)(ws + WS_FCWB);
  unsigned long long* pih_g = (unsigned long long*)(ws + WS_PIH);
  unsigned int*       prog1 = (unsigned int*)(ws + WS_FLAGS);

  hipMemsetAsync(ws + WS_FLAGS, 0, 4096, stream);
  pre_kernel<<<256, 128, 0, stream>>>(emb, x, W_ih0, b_ih0, b_hh0, pre0);
  fused_scan7<<<GRID_SCAN, 512, 0, stream>>>(pre0, W_hh0, W_ih1, W_hh1, b_ih1, b_hh1,
                                             h1b, pih_g, prog1, fc_W, fcWb);
  final_gemm5<<<8192, 256, 0, stream>>>(fcWb, h1b, fc_b, out);
}